// Round 12
// baseline (71.165 us; speedup 1.0000x reference)
//
#include <hip/hip_runtime.h>

// DCN cross net, round 11: TWO-PASS pure-stream split (round-10 retry; the
// readfirstlane(float) int-conversion bug poisoned S in pass 2 — now a plain
// uniform load, which HW broadcasts).
//  Pass 1 (read-only stream): S[row] from x-dots + scalar recurrence -> ws.
//  Pass 2 (write stream):     out = x*S + Bsum, elementwise; x re-read L3-hot.
// Fallback to the proven single-pass path if ws_size too small.

#define DCN_D 1024
#define DCN_F4 (DCN_D / 4)   // 256 float4 per row

__device__ __forceinline__ float dot4acc(const float4 a, const float4 b, float acc) {
    return fmaf(a.x, b.x, fmaf(a.y, b.y, fmaf(a.z, b.z, fmaf(a.w, b.w, acc))));
}

// const block layout at wc: [0..1023]=Bsum, [1024..1029]=c scalars
__global__ __launch_bounds__(256) void dcn_pre_kernel(
    const float* __restrict__ w,
    const float* __restrict__ b,
    float* __restrict__ wc)
{
    const int t = threadIdx.x;
    for (int d = t; d < DCN_D; d += 256)
        wc[d] = b[d] + b[DCN_D + d] + b[2 * DCN_D + d] + b[3 * DCN_D + d];
    float p[6] = {0, 0, 0, 0, 0, 0};
    for (int d = t; d < DCN_D; d += 256) {
        const float b0 = b[d], b1 = b[DCN_D + d], b2 = b[2 * DCN_D + d];
        const float w1 = w[DCN_D + d], w2 = w[2 * DCN_D + d], w3 = w[3 * DCN_D + d];
        p[0] = fmaf(b0, w1, p[0]);
        p[1] = fmaf(b0, w2, p[1]);
        p[2] = fmaf(b1, w2, p[2]);
        p[3] = fmaf(b0, w3, p[3]);
        p[4] = fmaf(b1, w3, p[4]);
        p[5] = fmaf(b2, w3, p[5]);
    }
    __shared__ float red[6][4];
    const int wave = t >> 6, lane = t & 63;
    #pragma unroll
    for (int k = 0; k < 6; ++k) {
        float v = p[k];
        #pragma unroll
        for (int off = 32; off > 0; off >>= 1) v += __shfl_down(v, off, 64);
        if (lane == 0) red[k][wave] = v;
    }
    __syncthreads();
    if (t < 6) wc[DCN_D + t] = red[t][0] + red[t][1] + red[t][2] + red[t][3];
}

// -------- Pass 1: S per row (pure read stream) --------
__global__ __launch_bounds__(256) void dcn_dots_kernel(
    const float* __restrict__ x,
    const float* __restrict__ w,
    const float* __restrict__ wc,
    float* __restrict__ S,          // [B]
    int B)
{
    const int wid  = (int)((blockIdx.x * 256u + threadIdx.x) >> 6);
    const int lane = (int)(threadIdx.x & 63);
    const int row0 = wid * 2;
    if (row0 >= B) return;

    const float4* __restrict__ xr0 =
        reinterpret_cast<const float4*>(x + (size_t)row0 * DCN_D);
    const float4* __restrict__ xr1 =
        reinterpret_cast<const float4*>(x + (size_t)(row0 + 1) * DCN_D);
    const float4* __restrict__ w4 = reinterpret_cast<const float4*>(w);

    float4 xa[4], xb[4];
    #pragma unroll
    for (int j = 0; j < 4; ++j) xa[j] = xr0[lane + 64 * j];
    #pragma unroll
    for (int j = 0; j < 4; ++j) xb[j] = xr1[lane + 64 * j];

    float p0[4] = {0, 0, 0, 0}, p1[4] = {0, 0, 0, 0};
    #pragma unroll
    for (int j = 0; j < 4; ++j) {
        const int idx = lane + 64 * j;
        #pragma unroll
        for (int l = 0; l < 4; ++l) {
            const float4 wv = w4[l * DCN_F4 + idx];   // L1-resident broadcast
            p0[l] = dot4acc(xa[j], wv, p0[l]);
            p1[l] = dot4acc(xb[j], wv, p1[l]);
        }
    }
    #pragma unroll
    for (int off = 1; off < 64; off <<= 1) {
        #pragma unroll
        for (int l = 0; l < 4; ++l) {
            p0[l] += __shfl_xor(p0[l], off, 64);
            p1[l] += __shfl_xor(p1[l], off, 64);
        }
    }

    const float c01   = wc[DCN_D + 0];
    const float c2sum = wc[DCN_D + 1] + wc[DCN_D + 2];
    const float c3sum = wc[DCN_D + 3] + wc[DCN_D + 4] + wc[DCN_D + 5];

    const float t1a = 1.f + p0[0];
    const float s1a = fmaf(p0[1], t1a, c01);
    const float t2a = t1a + s1a;
    const float s2a = fmaf(p0[2], t2a, c2sum);
    const float t3a = t2a + s2a;
    const float s3a = fmaf(p0[3], t3a, c3sum);
    const float t1b = 1.f + p1[0];
    const float s1b = fmaf(p1[1], t1b, c01);
    const float t2b = t1b + s1b;
    const float s2b = fmaf(p1[2], t2b, c2sum);
    const float t3b = t2b + s2b;
    const float s3b = fmaf(p1[3], t3b, c3sum);

    if (lane == 0) {
        S[row0]     = t3a + s3a;
        S[row0 + 1] = t3b + s3b;
    }
}

// -------- Pass 2: out = x*S + Bsum (pure write-dominant stream) --------
__global__ __launch_bounds__(256) void dcn_update_kernel(
    const float* __restrict__ x,
    const float* __restrict__ S,
    const float* __restrict__ wc,   // Bsum at wc[0..1023]
    float* __restrict__ out,
    int B)
{
    const int wid  = (int)((blockIdx.x * 256u + threadIdx.x) >> 6);
    const int lane = (int)(threadIdx.x & 63);
    const int row0 = wid * 2;
    if (row0 >= B) return;

    // uniform loads: HW broadcasts same-address wave loads
    const float S0 = S[row0];
    const float S1 = S[row0 + 1];

    const float4* __restrict__ xr0 =
        reinterpret_cast<const float4*>(x + (size_t)row0 * DCN_D);
    const float4* __restrict__ xr1 =
        reinterpret_cast<const float4*>(x + (size_t)(row0 + 1) * DCN_D);
    const float4* __restrict__ bs4 = reinterpret_cast<const float4*>(wc);
    float4* __restrict__ o0 = reinterpret_cast<float4*>(out + (size_t)row0 * DCN_D);
    float4* __restrict__ o1 = reinterpret_cast<float4*>(out + (size_t)(row0 + 1) * DCN_D);

    #pragma unroll
    for (int j = 0; j < 4; ++j) {
        const int idx = lane + 64 * j;
        const float4 xa = xr0[idx];
        const float4 xb = xr1[idx];
        const float4 bb = bs4[idx];
        float4 a;
        a.x = fmaf(xa.x, S0, bb.x);
        a.y = fmaf(xa.y, S0, bb.y);
        a.z = fmaf(xa.z, S0, bb.z);
        a.w = fmaf(xa.w, S0, bb.w);
        o0[idx] = a;
        float4 c;
        c.x = fmaf(xb.x, S1, bb.x);
        c.y = fmaf(xb.y, S1, bb.y);
        c.z = fmaf(xb.z, S1, bb.z);
        c.w = fmaf(xb.w, S1, bb.w);
        o1[idx] = c;
    }
}

// -------- Fallback single-pass (round-4 proven) --------
__global__ __launch_bounds__(256) void dcn_main_fallback(
    const float* __restrict__ x,
    const float* __restrict__ w,
    const float* __restrict__ wc,
    float* __restrict__ out,
    int B)
{
    const int wid  = (int)((blockIdx.x * 256u + threadIdx.x) >> 6);
    const int lane = (int)(threadIdx.x & 63);
    const int row0 = wid * 2;
    if (row0 >= B) return;

    const float4* __restrict__ xr0 =
        reinterpret_cast<const float4*>(x + (size_t)row0 * DCN_D);
    const float4* __restrict__ xr1 =
        reinterpret_cast<const float4*>(x + (size_t)(row0 + 1) * DCN_D);
    const float4* __restrict__ w4  = reinterpret_cast<const float4*>(w);
    float4 xa[4], xb[4];
    #pragma unroll
    for (int j = 0; j < 4; ++j) xa[j] = xr0[lane + 64 * j];
    #pragma unroll
    for (int j = 0; j < 4; ++j) xb[j] = xr1[lane + 64 * j];

    float p0[4] = {0, 0, 0, 0}, p1[4] = {0, 0, 0, 0};
    #pragma unroll
    for (int j = 0; j < 4; ++j) {
        const int idx = lane + 64 * j;
        #pragma unroll
        for (int l = 0; l < 4; ++l) {
            const float4 wv = w4[l * DCN_F4 + idx];
            p0[l] = dot4acc(xa[j], wv, p0[l]);
            p1[l] = dot4acc(xb[j], wv, p1[l]);
        }
    }
    #pragma unroll
    for (int off = 1; off < 64; off <<= 1) {
        #pragma unroll
        for (int l = 0; l < 4; ++l) {
            p0[l] += __shfl_xor(p0[l], off, 64);
            p1[l] += __shfl_xor(p1[l], off, 64);
        }
    }
    const float c01   = wc[DCN_D + 0];
    const float c2sum = wc[DCN_D + 1] + wc[DCN_D + 2];
    const float c3sum = wc[DCN_D + 3] + wc[DCN_D + 4] + wc[DCN_D + 5];
    const float t1a = 1.f + p0[0];
    const float s1a = fmaf(p0[1], t1a, c01);
    const float t2a = t1a + s1a;
    const float s2a = fmaf(p0[2], t2a, c2sum);
    const float t3a = t2a + s2a;
    const float s3a = fmaf(p0[3], t3a, c3sum);
    const float S0  = t3a + s3a;
    const float t1b = 1.f + p1[0];
    const float s1b = fmaf(p1[1], t1b, c01);
    const float t2b = t1b + s1b;
    const float s2b = fmaf(p1[2], t2b, c2sum);
    const float t3b = t2b + s2b;
    const float s3b = fmaf(p1[3], t3b, c3sum);
    const float S1  = t3b + s3b;

    const float4* __restrict__ bs4 = reinterpret_cast<const float4*>(wc);
    float4* __restrict__ o0 = reinterpret_cast<float4*>(out + (size_t)row0 * DCN_D);
    float4* __restrict__ o1 = reinterpret_cast<float4*>(out + (size_t)(row0 + 1) * DCN_D);
    #pragma unroll
    for (int j = 0; j < 4; ++j) {
        const int idx = lane + 64 * j;
        const float4 bb = bs4[idx];
        float4 a;
        a.x = fmaf(xa[j].x, S0, bb.x);
        a.y = fmaf(xa[j].y, S0, bb.y);
        a.z = fmaf(xa[j].z, S0, bb.z);
        a.w = fmaf(xa[j].w, S0, bb.w);
        o0[idx] = a;
        float4 c;
        c.x = fmaf(xb[j].x, S1, bb.x);
        c.y = fmaf(xb[j].y, S1, bb.y);
        c.z = fmaf(xb[j].z, S1, bb.z);
        c.w = fmaf(xb[j].w, S1, bb.w);
        o1[idx] = c;
    }
}

extern "C" void kernel_launch(void* const* d_in, const int* in_sizes, int n_in,
                              void* d_out, int out_size, void* d_ws, size_t ws_size,
                              hipStream_t stream) {
    const float* x = (const float*)d_in[0];
    const float* w = (const float*)d_in[1];
    const float* b = (const float*)d_in[2];
    float* out = (float*)d_out;
    float* ws = (float*)d_ws;
    const int B = in_sizes[0] / DCN_D;

    const size_t need = ((size_t)B + DCN_D + 16) * sizeof(float);
    const int rows_per_block = 8;   // 2 rows/wave x 4 waves
    const int grid = (B + rows_per_block - 1) / rows_per_block;

    if (ws_size >= need) {
        float* S  = ws;            // [B]
        float* wc = ws + B;        // constants block (1024 + 6)
        dcn_pre_kernel<<<1, 256, 0, stream>>>(w, b, wc);
        dcn_dots_kernel<<<grid, 256, 0, stream>>>(x, w, wc, S, B);
        dcn_update_kernel<<<grid, 256, 0, stream>>>(x, S, wc, out, B);
    } else {
        float* wc = ws;
        dcn_pre_kernel<<<1, 256, 0, stream>>>(w, b, wc);
        dcn_main_fallback<<<grid, 256, 0, stream>>>(x, w, wc, out, B);
    }
}

// Round 13
// 51.663 us; speedup vs baseline: 1.3775x; 1.3775x over previous
//
#include <hip/hip_runtime.h>

// DCN cross net, algebraically unrolled — FINAL (round-4 structure, best
// measured: 50.0 us). Six structural variants (r2/r4/r6/r8/r9/r11) all
// equilibrate at ~5.2-5.5 TB/s mixed read+write fabric BW; traffic here is
// the algorithmic minimum (128 MB x-read + 131 MB out-write), so this sits
// at ~96% of the demonstrated mixed-stream ceiling.
//   d_l = x0.w_l ; s0=d0; s1=d1(1+s0)+c01; s2=d2(1+s0+s1)+c02+c12;
//   s3=d3(1+s0+s1+s2)+c03+c13+c23 ; out = x0*(1+sum s_l) + Bsum
// c_{jl}=b_j.w_l and Bsum precomputed by a tiny pre-kernel into ws.

#define DCN_D 1024
#define DCN_F4 (DCN_D / 4)   // 256 float4 per row

// ws layout: ws[0..1023] = Bsum; ws[1024..1029] = {c01,c02,c12,c03,c13,c23}

__global__ __launch_bounds__(256) void dcn_pre_kernel(
    const float* __restrict__ w,   // [4, D]
    const float* __restrict__ b,   // [4, D]
    float* __restrict__ ws)
{
    const int t = threadIdx.x;
    for (int d = t; d < DCN_D; d += 256)
        ws[d] = b[d] + b[DCN_D + d] + b[2 * DCN_D + d] + b[3 * DCN_D + d];
    float p[6] = {0, 0, 0, 0, 0, 0};
    for (int d = t; d < DCN_D; d += 256) {
        const float b0 = b[d], b1 = b[DCN_D + d], b2 = b[2 * DCN_D + d];
        const float w1 = w[DCN_D + d], w2 = w[2 * DCN_D + d], w3 = w[3 * DCN_D + d];
        p[0] = fmaf(b0, w1, p[0]);
        p[1] = fmaf(b0, w2, p[1]);
        p[2] = fmaf(b1, w2, p[2]);
        p[3] = fmaf(b0, w3, p[3]);
        p[4] = fmaf(b1, w3, p[4]);
        p[5] = fmaf(b2, w3, p[5]);
    }
    __shared__ float red[6][4];
    const int wave = t >> 6, lane = t & 63;
    #pragma unroll
    for (int k = 0; k < 6; ++k) {
        float v = p[k];
        #pragma unroll
        for (int off = 32; off > 0; off >>= 1) v += __shfl_down(v, off, 64);
        if (lane == 0) red[k][wave] = v;
    }
    __syncthreads();
    if (t < 6) ws[DCN_D + t] = red[t][0] + red[t][1] + red[t][2] + red[t][3];
}

__device__ __forceinline__ float dcn_scalar_S(const float p[4], const float* cw) {
    const float c01 = cw[0], c02 = cw[1], c12 = cw[2];
    const float c03 = cw[3], c13 = cw[4], c23 = cw[5];
    const float s0 = p[0];
    const float t1 = 1.f + s0;
    const float s1 = fmaf(p[1], t1, c01);
    const float t2 = t1 + s1;
    const float s2 = fmaf(p[2], t2, c02 + c12);
    const float t3 = t2 + s2;
    const float s3 = fmaf(p[3], t3, c03 + c13 + c23);
    return t3 + s3;
}

__global__ __launch_bounds__(256) void dcn_main_kernel(
    const float* __restrict__ x,
    const float* __restrict__ w,
    const float* __restrict__ ws,
    float* __restrict__ out,
    int B)
{
    const int wgid = (int)((blockIdx.x * 256u + threadIdx.x) >> 6);  // global wave id
    const int lane = threadIdx.x & 63;
    const int row0 = wgid * 2;
    if (row0 >= B) return;
    const bool has2 = (row0 + 1) < B;
    const int row1 = has2 ? row0 + 1 : row0;

    const float4* __restrict__ xr0 = reinterpret_cast<const float4*>(x + (size_t)row0 * DCN_D);
    const float4* __restrict__ xr1 = reinterpret_cast<const float4*>(x + (size_t)row1 * DCN_D);
    const float4* __restrict__ w4  = reinterpret_cast<const float4*>(w);

    // issue all x loads up-front (8 outstanding HBM loads)
    float4 xv0[4], xv1[4];
    #pragma unroll
    for (int j = 0; j < 4; ++j) xv0[j] = xr0[lane + 64 * j];
    #pragma unroll
    for (int j = 0; j < 4; ++j) xv1[j] = xr1[lane + 64 * j];

    float p0[4] = {0, 0, 0, 0}, p1[4] = {0, 0, 0, 0};
    #pragma unroll
    for (int j = 0; j < 4; ++j) {
        const int idx = lane + 64 * j;
        #pragma unroll
        for (int l = 0; l < 4; ++l) {
            const float4 wv = w4[l * DCN_F4 + idx];   // L1-resident, shared by both rows
            p0[l] = fmaf(xv0[j].x, wv.x, fmaf(xv0[j].y, wv.y,
                    fmaf(xv0[j].z, wv.z, fmaf(xv0[j].w, wv.w, p0[l]))));
            p1[l] = fmaf(xv1[j].x, wv.x, fmaf(xv1[j].y, wv.y,
                    fmaf(xv1[j].z, wv.z, fmaf(xv1[j].w, wv.w, p1[l]))));
        }
    }

    // 8 independent butterfly reductions, pipelined
    #pragma unroll
    for (int off = 1; off < 64; off <<= 1) {
        #pragma unroll
        for (int l = 0; l < 4; ++l) {
            p0[l] += __shfl_xor(p0[l], off, 64);
            p1[l] += __shfl_xor(p1[l], off, 64);
        }
    }

    const float* cw = ws + DCN_D;
    const float S0 = dcn_scalar_S(p0, cw);
    const float S1 = dcn_scalar_S(p1, cw);

    const float4* __restrict__ bs4 = reinterpret_cast<const float4*>(ws);
    float4* __restrict__ o0 = reinterpret_cast<float4*>(out + (size_t)row0 * DCN_D);
    float4* __restrict__ o1 = reinterpret_cast<float4*>(out + (size_t)row1 * DCN_D);
    #pragma unroll
    for (int j = 0; j < 4; ++j) {
        const int idx = lane + 64 * j;
        const float4 bb = bs4[idx];               // L1-resident
        float4 a;
        a.x = fmaf(xv0[j].x, S0, bb.x);
        a.y = fmaf(xv0[j].y, S0, bb.y);
        a.z = fmaf(xv0[j].z, S0, bb.z);
        a.w = fmaf(xv0[j].w, S0, bb.w);
        o0[idx] = a;
        if (has2) {
            float4 c;
            c.x = fmaf(xv1[j].x, S1, bb.x);
            c.y = fmaf(xv1[j].y, S1, bb.y);
            c.z = fmaf(xv1[j].z, S1, bb.z);
            c.w = fmaf(xv1[j].w, S1, bb.w);
            o1[idx] = c;
        }
    }
}

extern "C" void kernel_launch(void* const* d_in, const int* in_sizes, int n_in,
                              void* d_out, int out_size, void* d_ws, size_t ws_size,
                              hipStream_t stream) {
    const float* x = (const float*)d_in[0];
    const float* w = (const float*)d_in[1];
    const float* b = (const float*)d_in[2];
    float* out = (float*)d_out;
    float* ws = (float*)d_ws;
    const int B = in_sizes[0] / DCN_D;

    dcn_pre_kernel<<<1, 256, 0, stream>>>(w, b, ws);
    // 2 rows per wave, 4 waves per block -> 8 rows per block
    const int rows_per_block = 8;
    dcn_main_kernel<<<(B + rows_per_block - 1) / rows_per_block, 256, 0, stream>>>(
        x, w, ws, out, B);
}